// Round 2
// baseline (1920.242 us; speedup 1.0000x reference)
//
#include <hip/hip_runtime.h>

#define B_   8
#define C_   96
#define H_   160
#define W_   320
#define MH   4
#define MW   4
#define ND   9            // offsets per dim (2*4+1)
#define NDD  81           // total offsets
#define TH   16
#define TW   32
#define HR   (TH + 2*MH)  // 24 halo rows
#define HWW  (TW + 2*MW)  // 40 halo cols
#define KC   8            // channels per LDS chunk
#define NCH  (C_/KC)      // 12 chunks
#define F1S  36           // f1 LDS row stride (36%32=4 spreads bank phases)
#define F2S  44           // f2 LDS row stride (44%32=12 spreads bank phases)
#define F1PLANE (TH*F1S)          // 576 words per channel
#define F2PLANE (HR*F2S)          // 1056 words per channel
#define F2OFF   (KC*F1PLANE)      // 4608
#define BUFW    (KC*(F1PLANE+F2PLANE))  // 13056 words = 52224 B per buffer
#define LDSWORDS (2*BUFW)         // double-buffered: 104448 B (1 block/CU by design)

__global__ __launch_bounds__(576, 2) void corr_kernel(
    const float* __restrict__ f1g,
    const float* __restrict__ f2g,
    float* __restrict__ out)
{
    __shared__ float lds[LDSWORDS];

    const int tid  = threadIdx.x;
    const int wave = tid >> 6;        // dh index 0..8 (this wave's row offset)
    const int lane = tid & 63;
    const int row  = lane >> 2;       // 0..15 (output row within tile)
    const int colb = (lane & 3) * 8;  // 0,8,16,24 (output col base; 8 px/thread)

    const int x0 = blockIdx.x * TW;
    const int y0 = blockIdx.y * TH;
    const int b  = blockIdx.z;
    const int HWi = H_ * W_;

    // ---------------- staging descriptors (prologue-only math) ----------------
    // f1: threads 0..511 stage one word per channel. Always in-bounds.
    const bool doF1  = tid < (TH * TW);
    const int  f1r   = tid >> 5;
    const int  f1c   = tid & 31;
    const int  f1goff = ((b * C_) * H_ + (y0 + f1r)) * W_ + x0 + f1c; // + c*HW
    const int  f1loff = f1r * F1S + f1c;

    // f2 halo (24x40 = 960 words/channel), pass A: word tid (all 576 threads)
    const int  rA = tid / HWW, cA = tid % HWW;
    const int  gyA = y0 - MH + rA, gxA = x0 - MW + cA;
    const bool inbA = (gyA >= 0) && (gyA < H_) && (gxA >= 0) && (gxA < W_);
    const int  f2goffA = ((b * C_) * H_ + gyA) * W_ + gxA;
    const int  f2loffA = rA * F2S + cA;

    // pass B: word 576+tid for tid<384
    const bool doB = tid < (HR * HWW - TH * TW - 64); // 384
    const int  wB = TH * TW + 64 + tid;               // 576+tid
    const int  rB = wB / HWW, cB = wB % HWW;
    const int  gyB = y0 - MH + rB, gxB = x0 - MW + cB;
    const bool inbB = doB && (gyB >= 0) && (gyB < H_) && (gxB >= 0) && (gxB < W_);
    const int  f2goffB = ((b * C_) * H_ + gyB) * W_ + gxB;
    const int  f2loffB = rB * F2S + cB;

    // compute-side LDS read bases (word offsets; all 16B-aligned)
    const int f1readbase = row * F1S + colb;
    const int f2readbase = (row + wave) * F2S + colb;  // halo row = out row + dh

    float acc[8][ND];
#pragma unroll
    for (int i = 0; i < 8; ++i)
#pragma unroll
        for (int d = 0; d < ND; ++d) acc[i][d] = 0.f;

    // staging registers (one chunk in flight)
    float s1[KC], s2a[KC], s2b[KC];

#define LOAD_CHUNK(CH)                                                       \
    {                                                                        \
        const int cb_ = (CH) * KC;                                           \
        _Pragma("unroll")                                                    \
        for (int c = 0; c < KC; ++c) {                                       \
            float v1 = 0.f, va = 0.f, vb = 0.f;                              \
            if (doF1) v1 = f1g[f1goff + (cb_ + c) * HWi];                    \
            if (inbA) va = f2g[f2goffA + (cb_ + c) * HWi];                   \
            if (inbB) vb = f2g[f2goffB + (cb_ + c) * HWi];                   \
            s1[c] = v1; s2a[c] = va; s2b[c] = vb;                            \
        }                                                                    \
    }

#define COMMIT_CHUNK(BASE)                                                   \
    {                                                                        \
        _Pragma("unroll")                                                    \
        for (int c = 0; c < KC; ++c) {                                       \
            if (doF1) lds[(BASE) + c * F1PLANE + f1loff] = s1[c];            \
            lds[(BASE) + F2OFF + c * F2PLANE + f2loffA] = s2a[c];            \
            if (doB)  lds[(BASE) + F2OFF + c * F2PLANE + f2loffB] = s2b[c];  \
        }                                                                    \
    }

    // ---- prologue: chunk 0 -> buf 0 ----
    LOAD_CHUNK(0);
    COMMIT_CHUNK(0);
    __syncthreads();

#pragma unroll 1
    for (int ch = 0; ch < NCH; ++ch) {
        const int rb = (ch & 1) * BUFW;
        const int wb = ((ch + 1) & 1) * BUFW;
        // issue next chunk's global loads first (latency hides under compute)
        if (ch + 1 < NCH) LOAD_CHUNK(ch + 1);
        // compute current chunk from lds[rb]
#pragma unroll
        for (int c = 0; c < KC; ++c) {
            const float4* p1 = (const float4*)&lds[rb + c * F1PLANE + f1readbase];
            const float4  a0 = p1[0], a1 = p1[1];
            const float4* p2 = (const float4*)&lds[rb + F2OFF + c * F2PLANE + f2readbase];
            const float4  b0 = p2[0], b1 = p2[1], b2 = p2[2], b3 = p2[3];
            const float f1v[8]  = {a0.x,a0.y,a0.z,a0.w,a1.x,a1.y,a1.z,a1.w};
            const float f2v[16] = {b0.x,b0.y,b0.z,b0.w,b1.x,b1.y,b1.z,b1.w,
                                   b2.x,b2.y,b2.z,b2.w,b3.x,b3.y,b3.z,b3.w};
#pragma unroll
            for (int i = 0; i < 8; ++i)
#pragma unroll
                for (int d = 0; d < ND; ++d)
                    acc[i][d] = fmaf(f1v[i], f2v[i + d], acc[i][d]);
        }
        // write next chunk into the other buffer (vmcnt wait auto-inserted)
        if (ch + 1 < NCH) COMMIT_CHUNK(wb);
        __syncthreads();
    }

    // ---- epilogue: out[b, wave*9+d, y0+row, x0+colb+i] ----
    const int gy = y0 + row;
    const int gx = x0 + colb;
#pragma unroll
    for (int d = 0; d < ND; ++d) {
        float4 v0, v1;
        v0.x = acc[0][d]; v0.y = acc[1][d]; v0.z = acc[2][d]; v0.w = acc[3][d];
        v1.x = acc[4][d]; v1.y = acc[5][d]; v1.z = acc[6][d]; v1.w = acc[7][d];
        float* op = out + (((long)(b * NDD + wave * ND + d) * H_ + gy)) * W_ + gx;
        *(float4*)(op)     = v0;
        *(float4*)(op + 4) = v1;
    }
}

extern "C" void kernel_launch(void* const* d_in, const int* in_sizes, int n_in,
                              void* d_out, int out_size, void* d_ws, size_t ws_size,
                              hipStream_t stream)
{
    const float* f1 = (const float*)d_in[0];
    const float* f2 = (const float*)d_in[1];
    float* out = (float*)d_out;
    dim3 grid(W_ / TW, H_ / TH, B_);  // 10 x 10 x 8 = 800 blocks
    corr_kernel<<<grid, 576, 0, stream>>>(f1, f2, out);
}

// Round 3
// 1034.045 us; speedup vs baseline: 1.8570x; 1.8570x over previous
//
#include <hip/hip_runtime.h>

#define B_   8
#define C_   96
#define H_   160
#define W_   320
#define ND   9             // offsets per dim
#define NDD  81
#define TH   16
#define TW   16
#define HR   24            // TH + 8 halo rows
#define HWW  24            // TW + 8 halo cols  (24*24 = 576 = blockDim: 1 word/thread/channel)
#define KC   8             // channels per chunk
#define NCH  12
#define F1S  20            // f1 LDS row stride (pad 4)
#define F2S  28            // f2 LDS row stride (pad 4)
#define F1PLANE (TH*F1S)          // 320 words/channel
#define F2PLANE (HR*F2S)          // 672 words/channel
#define F2OFF   (KC*F1PLANE)      // 2560
#define BUFW    (KC*(F1PLANE+F2PLANE))  // 7936 words = 31744 B
#define LDSWORDS (2*BUFW)         // 63488 B double-buffered -> 2 blocks/CU

#define REP8(M) M(0) M(1) M(2) M(3) M(4) M(5) M(6) M(7)

__global__ __launch_bounds__(576)
__attribute__((amdgpu_waves_per_eu(2, 4)))
void corr_kernel(const float* __restrict__ f1g,
                 const float* __restrict__ f2g,
                 float* __restrict__ out)
{
    __shared__ float lds[LDSWORDS];

    const int tid  = threadIdx.x;
    const int wave = tid >> 6;         // dh index 0..8
    const int lane = tid & 63;
    const int row  = lane >> 2;        // 0..15 output row in tile
    const int colb = (lane & 3) * 4;   // 0,4,8,12: 4 px per thread

    const int x0 = blockIdx.x * TW;
    const int y0 = blockIdx.y * TH;
    const int b  = blockIdx.z;
    const int HWi = H_ * W_;

    // ---- staging descriptors ----
    // f1 tile 16x16 = 256 words/ch: threads 0..255, one word each
    const bool doF1   = tid < (TH * TW);
    const int  f1r    = tid >> 4;
    const int  f1c    = tid & 15;
    const int  f1goff = ((b * C_) * H_ + (y0 + f1r)) * W_ + x0 + f1c;
    const int  f1loff = f1r * F1S + f1c;

    // f2 halo 24x24 = 576 words/ch: exactly one word per thread
    const int  rA   = tid / HWW;
    const int  cA   = tid % HWW;
    const int  gyA  = y0 - 4 + rA;
    const int  gxA  = x0 - 4 + cA;
    const bool inbA = (gyA >= 0) && (gyA < H_) && (gxA >= 0) && (gxA < W_);
    const int  f2goffA = ((b * C_) * H_ + gyA) * W_ + gxA;
    const int  f2loffA = rA * F2S + cA;

    // compute-side read bases (word offsets, 16B-aligned)
    const int f1readbase = row * F1S + colb;
    const int f2readbase = (row + wave) * F2S + colb;   // halo row = out row + dh

    // ---- named accumulators: acc<d> = float4 over the 4 pixels ----
    float4 acc0, acc1, acc2, acc3, acc4, acc5, acc6, acc7, acc8;
    acc0 = acc1 = acc2 = acc3 = acc4 = acc5 = acc6 = acc7 = acc8 = make_float4(0.f, 0.f, 0.f, 0.f);

    // ---- named staging registers ----
#define DECL_S(c) float s1_##c, s2_##c;
    REP8(DECL_S)

#define LOADC(c) {                                              \
        float v1_ = 0.f, v2_ = 0.f;                             \
        if (doF1) v1_ = f1g[f1goff + (cb_ + c) * HWi];          \
        if (inbA) v2_ = f2g[f2goffA + (cb_ + c) * HWi];         \
        s1_##c = v1_; s2_##c = v2_; }

#define COMMITC(c) {                                            \
        if (doF1) lds[wb_ + c * F1PLANE + f1loff] = s1_##c;     \
        lds[wb_ + F2OFF + c * F2PLANE + f2loffA] = s2_##c; }

    // px i (of 4), offset d: f2 window element n[i+d]
#define STEPD(A, P, e0, e1, e2, e3)                             \
        A.x = fmaf(P.x, e0, A.x);                               \
        A.y = fmaf(P.y, e1, A.y);                               \
        A.z = fmaf(P.z, e2, A.z);                               \
        A.w = fmaf(P.w, e3, A.w);

#define COMPC(c) {                                                             \
        const float4 P  = *(const float4*)&lds[rb_ + c * F1PLANE + f1readbase];\
        const float4 q0 = *(const float4*)&lds[rb_ + F2OFF + c * F2PLANE + f2readbase];     \
        const float4 q1 = *(const float4*)&lds[rb_ + F2OFF + c * F2PLANE + f2readbase + 4]; \
        const float4 q2 = *(const float4*)&lds[rb_ + F2OFF + c * F2PLANE + f2readbase + 8]; \
        STEPD(acc0, P, q0.x, q0.y, q0.z, q0.w)                                 \
        STEPD(acc1, P, q0.y, q0.z, q0.w, q1.x)                                 \
        STEPD(acc2, P, q0.z, q0.w, q1.x, q1.y)                                 \
        STEPD(acc3, P, q0.w, q1.x, q1.y, q1.z)                                 \
        STEPD(acc4, P, q1.x, q1.y, q1.z, q1.w)                                 \
        STEPD(acc5, P, q1.y, q1.z, q1.w, q2.x)                                 \
        STEPD(acc6, P, q1.z, q1.w, q2.x, q2.y)                                 \
        STEPD(acc7, P, q1.w, q2.x, q2.y, q2.z)                                 \
        STEPD(acc8, P, q2.x, q2.y, q2.z, q2.w)                                 \
    }

    // ---- prologue: chunk 0 -> buf 0 ----
    {
        const int cb_ = 0, wb_ = 0;
        REP8(LOADC)
        REP8(COMMITC)
    }
    __syncthreads();

#pragma unroll 1
    for (int ch = 0; ch < NCH; ++ch) {
        const int rb_ = (ch & 1) * BUFW;
        const int wb_ = ((ch + 1) & 1) * BUFW;
        if (ch + 1 < NCH) {
            const int cb_ = (ch + 1) * KC;
            REP8(LOADC)                 // issue next chunk's global loads early
        }
        REP8(COMPC)                     // compute current chunk from lds[rb_]
        if (ch + 1 < NCH) {
            REP8(COMMITC)               // write next chunk to the other buffer
        }
        __syncthreads();
    }

    // ---- epilogue: out[b, wave*9+d, y0+row, x0+colb .. +3] ----
    const int gy = y0 + row;
    const int gx = x0 + colb;
#define STORED(d) {                                                            \
        float* op_ = out + ((size_t)((b * NDD + wave * ND + d) * H_ + gy)) * W_ + gx; \
        *(float4*)op_ = acc##d; }
    STORED(0) STORED(1) STORED(2) STORED(3) STORED(4)
    STORED(5) STORED(6) STORED(7) STORED(8)
}

extern "C" void kernel_launch(void* const* d_in, const int* in_sizes, int n_in,
                              void* d_out, int out_size, void* d_ws, size_t ws_size,
                              hipStream_t stream)
{
    const float* f1 = (const float*)d_in[0];
    const float* f2 = (const float*)d_in[1];
    float* out = (float*)d_out;
    dim3 grid(W_ / TW, H_ / TH, B_);   // 20 x 10 x 8 = 1600 blocks
    corr_kernel<<<grid, 576, 0, stream>>>(f1, f2, out);
}

// Round 4
// 245.005 us; speedup vs baseline: 7.8376x; 4.2205x over previous
//
#include <hip/hip_runtime.h>

#define B_   8
#define C_   96
#define H_   160
#define W_   320
#define ND   9
#define NDD  81
#define TH   16
#define TW   16
#define KC   8
#define NCH  12
#define F1PLANE 256                      // 16x16 dwords, unpadded (stride 16)
#define F2PLANE 576                      // 24x24 dwords, unpadded (stride 24)
#define F2OFF   (KC*F1PLANE)             // 2048
#define BUFW    (KC*(F1PLANE+F2PLANE))   // 6656 dwords = 26624 B
#define LDSWORDS (2*BUFW)                // 53248 B -> 3 blocks/CU by LDS

#define AS1 __attribute__((address_space(1)))
#define AS3 __attribute__((address_space(3)))

__device__ __forceinline__ void gld16(const float* gp, const float* lp) {
    // HBM -> LDS direct, 16B/lane; LDS dest = uniform base + lane*16
    __builtin_amdgcn_global_load_lds((const AS1 float*)gp,
                                     (AS3 float*)(unsigned long long)lp, 16, 0, 0);
}
__device__ __forceinline__ void gld4(const float* gp, const float* lp) {
    __builtin_amdgcn_global_load_lds((const AS1 float*)gp,
                                     (AS3 float*)(unsigned long long)lp, 4, 0, 0);
}

__global__ __launch_bounds__(576)
void corr_kernel(const float* __restrict__ f1g,
                 const float* __restrict__ f2g,
                 float* __restrict__ out)
{
    __shared__ float lds[LDSWORDS];

    const int tid  = threadIdx.x;
    const int wave = tid >> 6;          // dh 0..8
    const int lane = tid & 63;
    const int row  = lane >> 2;         // 0..15
    const int colb = (lane & 3) * 4;    // 0,4,8,12

    // XCD-contiguous tiles: 1600 blocks = 8 XCDs x 200; XCD k gets batch k.
    const int bid  = blockIdx.x;
    const int ebid = (bid & 7) * 200 + (bid >> 3);
    const int b    = ebid / 200;
    const int rr   = ebid - b * 200;
    const int by   = rr / 20;
    const int bx   = rr - by * 20;
    const int x0 = bx * TW, y0 = by * TH;
    const int HWi  = H_ * W_;
    const int base1 = b * C_ * HWi;     // channel-0 plane for this batch

    // zero LDS once: exec-masked (OOB) gld slots stay zero forever
    for (int i = tid; i < LDSWORDS; i += 576) lds[i] = 0.f;

    // ---- per-lane staging descriptors (prologue only) ----
    // f1 width16: lane -> (r=lane>>2, c=(lane&3)*4), always in-bounds
    const int f1goff = base1 + (y0 + (lane >> 2)) * W_ + x0 + (lane & 3) * 4;
    // f2 plane flat layout [24][24]; part0: flat=lane*4, part1: 256+lane*4, part2(tail,4B): 512+lane
    int f2g0, f2g1, f2g2; bool f2p0, f2p1, f2p2;
    {
        int fl, r, c, y, x;
        fl = lane * 4;       r = fl / 24; c = fl - r * 24; y = y0 - 4 + r; x = x0 - 4 + c;
        f2p0 = (y >= 0) & (y < H_) & (x >= 0) & (x + 4 <= W_);  f2g0 = base1 + y * W_ + x;
        fl = 256 + lane * 4; r = fl / 24; c = fl - r * 24; y = y0 - 4 + r; x = x0 - 4 + c;
        f2p1 = (y >= 0) & (y < H_) & (x >= 0) & (x + 4 <= W_);  f2g1 = base1 + y * W_ + x;
        fl = 512 + lane;     r = fl / 24; c = fl - r * 24; y = y0 - 4 + r; x = x0 - 4 + c;
        f2p2 = (y >= 0) & (y < H_) & (x >= 0) & (x < W_);       f2g2 = base1 + y * W_ + x;
    }

    // compute-side LDS read bases (dword offsets, 16B-aligned)
    const int f1readbase = row * 16 + colb;
    const int f2readbase = (row + wave) * 24 + colb;   // halo row = out row + dh

    // issue one chunk's loads (32 segments = 8ch x {f1, f2a, f2b, f2tail}),
    // distributed across the 9 waves
    auto stage = [&](int cb, int wbase) {
        for (int s = wave; s < 4 * KC; s += 9) {
            const int ch   = s >> 2;
            const int part = s & 3;
            const int coff = (cb + ch) * HWi;
            if (part == 0) {
                gld16(f1g + f1goff + coff, &lds[wbase + ch * F1PLANE]);
            } else if (part == 1) {
                if (f2p0) gld16(f2g + f2g0 + coff, &lds[wbase + F2OFF + ch * F2PLANE]);
            } else if (part == 2) {
                if (f2p1) gld16(f2g + f2g1 + coff, &lds[wbase + F2OFF + ch * F2PLANE + 256]);
            } else {
                if (f2p2) gld4(f2g + f2g2 + coff, &lds[wbase + F2OFF + ch * F2PLANE + 512]);
            }
        }
    };

    // ---- named accumulators ----
    float4 acc0, acc1, acc2, acc3, acc4, acc5, acc6, acc7, acc8;
    acc0 = acc1 = acc2 = acc3 = acc4 = acc5 = acc6 = acc7 = acc8 = make_float4(0.f, 0.f, 0.f, 0.f);

#define STEPD(A, P, e0, e1, e2, e3)                             \
        A.x = fmaf(P.x, e0, A.x);                               \
        A.y = fmaf(P.y, e1, A.y);                               \
        A.z = fmaf(P.z, e2, A.z);                               \
        A.w = fmaf(P.w, e3, A.w);

#define COMPC(c) {                                                                  \
        const float4 P  = *(const float4*)&lds[rb_ + c * F1PLANE + f1readbase];     \
        const float4 q0 = *(const float4*)&lds[rb_ + F2OFF + c * F2PLANE + f2readbase];     \
        const float4 q1 = *(const float4*)&lds[rb_ + F2OFF + c * F2PLANE + f2readbase + 4]; \
        const float4 q2 = *(const float4*)&lds[rb_ + F2OFF + c * F2PLANE + f2readbase + 8]; \
        STEPD(acc0, P, q0.x, q0.y, q0.z, q0.w)                                      \
        STEPD(acc1, P, q0.y, q0.z, q0.w, q1.x)                                      \
        STEPD(acc2, P, q0.z, q0.w, q1.x, q1.y)                                      \
        STEPD(acc3, P, q0.w, q1.x, q1.y, q1.z)                                      \
        STEPD(acc4, P, q1.x, q1.y, q1.z, q1.w)                                      \
        STEPD(acc5, P, q1.y, q1.z, q1.w, q2.x)                                      \
        STEPD(acc6, P, q1.z, q1.w, q2.x, q2.y)                                      \
        STEPD(acc7, P, q1.w, q2.x, q2.y, q2.z)                                      \
        STEPD(acc8, P, q2.x, q2.y, q2.z, q2.w)                                      \
    }
#define REP8(M) M(0) M(1) M(2) M(3) M(4) M(5) M(6) M(7)

    __syncthreads();          // zeros visible before any DMA write
    stage(0, 0);              // chunk 0 -> buf 0
    __syncthreads();          // compiler drains vmcnt before barrier

#pragma unroll 1
    for (int ch = 0; ch < NCH; ++ch) {
        const int rb_ = (ch & 1) * BUFW;
        if (ch + 1 < NCH) stage((ch + 1) * KC, BUFW - rb_);  // prefetch next chunk
        REP8(COMPC)                                          // compute current
        __syncthreads();                                     // drain DMA + LDS reads
    }

    // ---- epilogue: out[b, wave*9+d, y0+row, x0+colb .. +3] ----
    const int gy = y0 + row;
    const int gx = x0 + colb;
#define STORED(d) {                                                                   \
        float* op_ = out + (size_t)((b * NDD + wave * ND + d) * H_ + gy) * W_ + gx;   \
        *(float4*)op_ = acc##d; }
    STORED(0) STORED(1) STORED(2) STORED(3) STORED(4)
    STORED(5) STORED(6) STORED(7) STORED(8)
}

extern "C" void kernel_launch(void* const* d_in, const int* in_sizes, int n_in,
                              void* d_out, int out_size, void* d_ws, size_t ws_size,
                              hipStream_t stream)
{
    const float* f1 = (const float*)d_in[0];
    const float* f2 = (const float*)d_in[1];
    float* out = (float*)d_out;
    corr_kernel<<<dim3(1600), 576, 0, stream>>>(f1, f2, out);
}

// Round 5
// 229.563 us; speedup vs baseline: 8.3648x; 1.0673x over previous
//
#include <hip/hip_runtime.h>

#define B_   8
#define C_   96
#define H_   160
#define W_   320
#define ND   9
#define NDD  81
#define TH   16
#define TW   16
#define KC   8
#define NCH  12
#define F1PLANE 256                 // 16x16 dwords per channel (linear, stride 16)
#define F2PLANE 576                 // 24x24 dwords per channel (linear, stride 24)
#define F2OFF   (KC*F1PLANE)        // 2048
#define BUFW    (KC*(F1PLANE+F2PLANE))   // 6656 dwords = 26624 B per buffer
#define NBUF    3
#define LDSWORDS (NBUF*BUFW)        // 19968 dw = 79872 B -> 2 blocks/CU

#define AS1 __attribute__((address_space(1)))
#define AS3 __attribute__((address_space(3)))

__device__ float g_zero[512];       // .bss zeros; never written -> stays zero

__device__ __forceinline__ void gld16(const float* gp, const float* lp) {
    __builtin_amdgcn_global_load_lds((const AS1 float*)gp,
                                     (AS3 float*)(unsigned long long)lp, 16, 0, 0);
}
__device__ __forceinline__ void gld4(const float* gp, const float* lp) {
    __builtin_amdgcn_global_load_lds((const AS1 float*)gp,
                                     (AS3 float*)(unsigned long long)lp, 4, 0, 0);
}

__global__ __launch_bounds__(576)
void corr_kernel(const float* __restrict__ f1g,
                 const float* __restrict__ f2g,
                 float* __restrict__ out)
{
    __shared__ float lds[LDSWORDS];

    const int tid  = threadIdx.x;
    const int wave = tid >> 6;          // dh 0..8
    const int lane = tid & 63;
    const int row  = lane >> 2;         // 0..15
    const int colb = (lane & 3) * 4;    // 0,4,8,12

    // XCD swizzle: 1600 blocks = 8 XCDs x 200; XCD k owns batch k.
    const int bid  = blockIdx.x;
    const int ebid = (bid & 7) * 200 + (bid >> 3);
    const int b    = ebid / 200;
    const int rr   = ebid - b * 200;
    const int by   = rr / 20;
    const int bx   = rr - by * 20;
    const int x0 = bx * TW, y0 = by * TH;
    const int HWi  = H_ * W_;
    const int base1 = b * C_ * HWi;

    // ---- per-lane staging descriptors (prologue only) ----
    // f1 (waves<8): gld16 lane mapping == compute mapping (row, colb). Always in-bounds.
    const float* f1src = f1g + base1 + (y0 + row) * W_ + x0 + colb;

    // f2 parts (waves<8): plane [24][24] linear; part0 flat=lane*4, part1 flat=256+lane*4
    const float* p0; const float* p1; bool inb0, inb1;
    {
        int fl, r, c, y, x;
        fl = lane * 4;       r = fl / 24; c = fl - r * 24; y = y0 - 4 + r; x = x0 - 4 + c;
        inb0 = (y >= 0) & (y < H_) & (x >= 0) & (x + 4 <= W_);
        p0 = f2g + base1 + y * W_ + x;
        fl = 256 + lane * 4; r = fl / 24; c = fl - r * 24; y = y0 - 4 + r; x = x0 - 4 + c;
        inb1 = (y >= 0) & (y < H_) & (x >= 0) & (x + 4 <= W_);
        p1 = f2g + base1 + y * W_ + x;
    }
    // f2 tail (wave 8): flat = 512+lane, one dword per lane
    const float* pT; bool inbT;
    {
        int fl = 512 + lane;
        int r = fl / 24, c = fl - r * 24;
        int y = y0 - 4 + r, x = x0 - 4 + c;
        inbT = (y >= 0) & (y < H_) & (x >= 0) & (x < W_);
        pT = f2g + base1 + y * W_ + x;
    }
    const float* zl = g_zero + lane * 4;   // 16B/lane zero source
    const float* zt = g_zero + lane;       // 4B/lane zero source

    // compute-side LDS read bases (dword offsets, all 16B-aligned)
    const int f1readbase = row * 16 + colb;
    const int f2readbase = (row + wave) * 24 + colb;   // halo row = out row + dh

    // staging: wave w<8 -> {f1 ch w, f2 ch w part0, f2 ch w part1} (3x gld16)
    //          wave 8   -> 8x gld4 (f2 tails, ch 0..7)
    auto stage = [&](int cb, int bufb) {
        if (wave < 8) {
            const int coff = (cb + wave) * HWi;
            gld16(f1src + coff, &lds[bufb + wave * F1PLANE]);
            gld16(inb0 ? p0 + coff : zl, &lds[bufb + F2OFF + wave * F2PLANE]);
            gld16(inb1 ? p1 + coff : zl, &lds[bufb + F2OFF + wave * F2PLANE + 256]);
        } else {
#pragma unroll
            for (int c = 0; c < 8; ++c) {
                gld4(inbT ? pT + (cb + c) * HWi : zt,
                     &lds[bufb + F2OFF + c * F2PLANE + 512]);
            }
        }
    };

    // ---- named accumulators ----
    float4 acc0, acc1, acc2, acc3, acc4, acc5, acc6, acc7, acc8;
    acc0 = acc1 = acc2 = acc3 = acc4 = acc5 = acc6 = acc7 = acc8 = make_float4(0.f, 0.f, 0.f, 0.f);

#define STEPD(A, P, e0, e1, e2, e3)                             \
        A.x = fmaf(P.x, e0, A.x);                               \
        A.y = fmaf(P.y, e1, A.y);                               \
        A.z = fmaf(P.z, e2, A.z);                               \
        A.w = fmaf(P.w, e3, A.w);

#define COMPC(c) {                                                                  \
        const float4 P  = *(const float4*)&lds[rb_ + c * F1PLANE + f1readbase];     \
        const float4 q0 = *(const float4*)&lds[rb_ + F2OFF + c * F2PLANE + f2readbase];     \
        const float4 q1 = *(const float4*)&lds[rb_ + F2OFF + c * F2PLANE + f2readbase + 4]; \
        const float4 q2 = *(const float4*)&lds[rb_ + F2OFF + c * F2PLANE + f2readbase + 8]; \
        STEPD(acc0, P, q0.x, q0.y, q0.z, q0.w)                                      \
        STEPD(acc1, P, q0.y, q0.z, q0.w, q1.x)                                      \
        STEPD(acc2, P, q0.z, q0.w, q1.x, q1.y)                                      \
        STEPD(acc3, P, q0.w, q1.x, q1.y, q1.z)                                      \
        STEPD(acc4, P, q1.x, q1.y, q1.z, q1.w)                                      \
        STEPD(acc5, P, q1.y, q1.z, q1.w, q2.x)                                      \
        STEPD(acc6, P, q1.z, q1.w, q2.x, q2.y)                                      \
        STEPD(acc7, P, q1.w, q2.x, q2.y, q2.z)                                      \
        STEPD(acc8, P, q2.x, q2.y, q2.z, q2.w)                                      \
    }
#define REP8(M) M(0) M(1) M(2) M(3) M(4) M(5) M(6) M(7)

    // ---- prologue: prefetch chunks 0 and 1 ----
    stage(0, 0);
    stage(KC, BUFW);

#pragma unroll 1
    for (int k = 0; k < NCH; ++k) {
        // counted wait: own chunk-k segments retired (in-order), chunk-(k+1) may fly
        if (k + 1 < NCH) {
            if (wave < 8) { asm volatile("s_waitcnt vmcnt(3)" ::: "memory"); }
            else          { asm volatile("s_waitcnt vmcnt(8)" ::: "memory"); }
        } else {
            asm volatile("s_waitcnt vmcnt(0)" ::: "memory");
        }
        __builtin_amdgcn_s_barrier();   // all waves' chunk-k data in LDS; buf (k+2)%3 free
        if (k + 2 < NCH) stage((k + 2) * KC, ((k + 2) % 3) * BUFW);
        const int rb_ = (k % 3) * BUFW;
        REP8(COMPC)
    }

    // ---- epilogue: out[b, wave*9+d, y0+row, x0+colb .. +3] ----
    const int gy = y0 + row;
    const int gx = x0 + colb;
#define STORED(d) {                                                                   \
        float* op_ = out + (size_t)((b * NDD + wave * ND + d) * H_ + gy) * W_ + gx;   \
        *(float4*)op_ = acc##d; }
    STORED(0) STORED(1) STORED(2) STORED(3) STORED(4)
    STORED(5) STORED(6) STORED(7) STORED(8)
}

extern "C" void kernel_launch(void* const* d_in, const int* in_sizes, int n_in,
                              void* d_out, int out_size, void* d_ws, size_t ws_size,
                              hipStream_t stream)
{
    const float* f1 = (const float*)d_in[0];
    const float* f2 = (const float*)d_in[1];
    float* out = (float*)d_out;
    corr_kernel<<<dim3(1600), 576, 0, stream>>>(f1, f2, out);
}